// Round 5
// baseline (244.676 us; speedup 1.0000x reference)
//
#include <hip/hip_runtime.h>
#include <hip/hip_bf16.h>

typedef __hip_bfloat16 bf16;
typedef unsigned int uint32;
typedef __attribute__((ext_vector_type(8))) short short8;
typedef __attribute__((ext_vector_type(4))) float float4v;
typedef __attribute__((ext_vector_type(16))) float float16v;

#define THREADS 512
#define LDX 520  // sX row stride in bf16 (16B-aligned rows for ds_read_b128)
#define LDE 68   // sE row stride in f32
#define LOG2E 1.44269504088896340736f

__device__ __forceinline__ bf16 f2b(float x) { return __float2bfloat16(x); }
__device__ __forceinline__ uint32 packbf2(float x, float y) {
  union { __hip_bfloat162 b; uint32 u; } cv;
  cv.b = __float22bfloat162_rn(make_float2(x, y));
  return cv.u;
}
// single f32->bf16 via the packed HW convert (1 op), RNE
__device__ __forceinline__ bf16 f2b1(float x) {
  union { uint32 u; unsigned short s[2]; } cv;
  cv.u = packbf2(x, x);
  union { unsigned short s; bf16 b; } r;
  r.s = cv.s[0];
  return r.b;
}
// 2^x via v_exp_f32 (logits are pre-scaled by log2e at convE time)
__device__ __forceinline__ float exp2_hw(float x) {
#if __has_builtin(__builtin_amdgcn_exp2f)
  return __builtin_amdgcn_exp2f(x);
#else
  float r;
  asm("v_exp_f32 %0, %1" : "=v"(r) : "v"(x));
  return r;
#endif
}
__device__ __forceinline__ float rcp_hw(float x) {
#if __has_builtin(__builtin_amdgcn_rcpf)
  return __builtin_amdgcn_rcpf(x);
#else
  float r;
  asm("v_rcp_f32 %0, %1" : "=v"(r) : "v"(x));
  return r;
#endif
}
// lane<32 <-> lane>=32 half exchange. lo: own(a) for q=0 / partner(b) for q=1.
// hi: partner(a) for q=0 / own(b) for q=1. One v_permlane32_swap yields both;
// old operands die into the swap (saves the 4 select temps of the shfl form).
__device__ __forceinline__ void lane32_swap(uint32 a, uint32 b, int q,
                                            uint32& lo, uint32& hi) {
#if __has_builtin(__builtin_amdgcn_permlane32_swap)
  auto r = __builtin_amdgcn_permlane32_swap(a, b, false, false);
  lo = r[0];
  hi = r[1];
  (void)q;
#else
  uint32 pa = (uint32)__shfl_xor((int)a, 32, 64);
  uint32 pb = (uint32)__shfl_xor((int)b, 32, 64);
  lo = q ? pb : a;
  hi = q ? b : pa;
#endif
}

// ---- fused prep: part A (blocks 0..1599) converts W1/W2/W3 to the 32x32x16
// B-frag layout with COALESCED source reads (R4's gather version read at 2KB
// stride: 64 lines/wave-instr). Part B (blocks 1600..1863) computes the E
// tiles (W@a_src | W@a_dst per head, scaled by log2e) one WAVE per W-row:
// coalesced float4 row loads + per-lane dot + 8-lane-group shfl reduce.
// Replaces convE_all's 66-block, stride-2KB, 64-iter scalar-dot version.
__global__ void prep_all(const float* __restrict__ W1, const float* __restrict__ W2,
                         const float* __restrict__ W3,
                         const float* __restrict__ as1, const float* __restrict__ ad1,
                         const float* __restrict__ as2, const float* __restrict__ ad2,
                         const float* __restrict__ as3, const float* __restrict__ ad3,
                         bf16* __restrict__ dst, bf16* __restrict__ dstE) {
  const int b = blockIdx.x;
  const int t = threadIdx.x;
  if (b < 1600) {
    int o = b * 256 + t;  // source-linear over concat(W1,W2,W3): coalesced read
    const float* W;
    int Mlog, loc, dbase;
    if (o < 16384) { W = W1; Mlog = 9; loc = o; dbase = 0; }
    else if (o < 278528) { W = W2; Mlog = 9; loc = o - 16384; dbase = 16384; }
    else { W = W3; Mlog = 8; loc = o - 278528; dbase = 278528; }
    float v = W[loc];
    int M = 1 << Mlog;
    int n = loc & (M - 1), k = loc >> Mlog;
    int kb = k >> 4, q = (k >> 3) & 1, j = k & 7;
    // same dst mapping as before: dst[((kb*M+n)*2+q)*8+j], k = kb*16+q*8+j
    dst[dbase + ((kb * M + n) * 2 + q) * 8 + j] = f2b(v);
    return;
  }
  // ---- part B: one wave per k-row; 1056 rows total (32|512|512) ----
  const int kr = (b - 1600) * 4 + (t >> 6);
  const int l = t & 63;
  const float *W, *as_, *ad_;
  int M, lk, dbase;
  if (kr < 32)       { W = W1; as_ = as1; ad_ = ad1; M = 512; lk = kr;       dbase = 0; }
  else if (kr < 544) { W = W2; as_ = as2; ad_ = ad2; M = 512; lk = kr - 32;  dbase = 512; }
  else               { W = W3; as_ = as3; ad_ = ad3; M = 256; lk = kr - 544; dbase = 8704; }
  const float* wr = W + (size_t)lk * M;
  float ps = 0.f, pd = 0.f;
  if (M == 512) {
    // head h = l>>3 owns cols [h*64, h*64+64); lane's 8 cols start at m=8*l,
    // and a_flat[h*64 + c] == a_flat[8*l + i] for this lane (identity: 8l).
    float4 w0 = *(const float4*)(wr + 8 * l);
    float4 w1 = *(const float4*)(wr + 8 * l + 4);
    float4 s0 = *(const float4*)(as_ + 8 * l);
    float4 s1 = *(const float4*)(as_ + 8 * l + 4);
    float4 d0 = *(const float4*)(ad_ + 8 * l);
    float4 d1 = *(const float4*)(ad_ + 8 * l + 4);
    ps = w0.x * s0.x + w0.y * s0.y + w0.z * s0.z + w0.w * s0.w +
         w1.x * s1.x + w1.y * s1.y + w1.z * s1.z + w1.w * s1.w;
    pd = w0.x * d0.x + w0.y * d0.y + w0.z * d0.z + w0.w * d0.w +
         w1.x * d1.x + w1.y * d1.y + w1.z * d1.z + w1.w * d1.w;
  } else {
    // C=32: head h = l>>3 owns cols [h*32, h*32+32); lane's 4 cols at m=4*l.
    float4 w0 = *(const float4*)(wr + 4 * l);
    float4 s0 = *(const float4*)(as_ + 4 * l);
    float4 d0 = *(const float4*)(ad_ + 4 * l);
    ps = w0.x * s0.x + w0.y * s0.y + w0.z * s0.z + w0.w * s0.w;
    pd = w0.x * d0.x + w0.y * d0.y + w0.z * d0.z + w0.w * d0.w;
  }
  // butterfly reduce within each 8-lane head group
#pragma unroll
  for (int m = 1; m < 8; m <<= 1) {
    ps += __shfl_xor(ps, m, 64);
    pd += __shfl_xor(pd, m, 64);
  }
  const int j = lk & 7, kc = (lk >> 3) & 3, ks = lk >> 5;
  const int h = l >> 3;
  const int base = dbase + ks * 512 + kc * 8 + j;
  if ((l & 7) == 0) dstE[base + h * 32] = f2b(ps * LOG2E);
  if ((l & 7) == 1) dstE[base + (8 + h) * 32] = f2b(pd * LOG2E);
}

// One GAT layer on 32x32x16 MFMA. Wave w == head w (owns C output cols).
// Phase 1 single-pass: all 4 acc chains (64 regs) live; each A/B fragment
// loaded exactly once. h kept in regs as packed bf16 (Ppk); C/D -> B-frag
// transpose is a single v_permlane32_swap per dword pair (both halves out).
// REGISTER DISCIPLINE (R2/R3 lesson): __launch_bounds__(512,4) caps the
// unified VGPR+AGPR file at 128/wave; phase 1 holds 64 AGPR of accumulators.
// R0's structure (pe_ array + IMMEDIATE softmax normalization, oacc scoped
// per-ct, no extra LDS strip) allocates 60+64=124 with zero spill. The
// deferred-normalization variant pushed to 64+64=128 and spilled ~120 B/thread
// (WRITE_SIZE 2 MB -> 122-128 MB). Do not restructure register lifetimes here.
// T5: s_setprio(1) wraps the MFMA clusters — with 2 independent blocks/CU the
// CU scheduler has {MFMA-phase, VALU-phase} wave diversity to arbitrate.
template <int K, int M, int C, bool LAST>
__device__ __forceinline__ void gat_layer(
    int t, const bf16* __restrict__ Wswz, const bf16* __restrict__ WE,
    const float* __restrict__ bias, bf16* sX, float* sE) {
  constexpr int NCT = C / 32;   // 32-col tiles per wave (2 or 1)
  constexpr int KS16 = K / 16;  // 32x32x16 k-steps
  constexpr int KSE = K / 32;   // 16x16x32 k-steps for E
  const int lane = t & 63;
  const int hu = __builtin_amdgcn_readfirstlane(t >> 6);  // wave/head id
  const int c = lane & 31, q = lane >> 5;
  const int ln16 = lane & 15, kq16 = lane >> 4;
  const int colbase = hu * C;

  // ---- E-tile (ls|ld for ALL heads), waves 0-3, 16x16x32 path ----
  if (hu < 4) {
    float4v acce = (float4v)0.f;
#pragma unroll
    for (int ks = 0; ks < KSE; ++ks) {
      short8 afrE = *(const short8*)(sX + (hu * 16 + ln16) * LDX + ks * 32 + kq16 * 8);
      short8 efr = *(const short8*)(WE + ks * 512 + ln16 * 32 + kq16 * 8);
      __builtin_amdgcn_s_setprio(1);
      acce = __builtin_amdgcn_mfma_f32_16x16x32_bf16(afrE, efr, acce, 0, 0, 0);
      __builtin_amdgcn_s_setprio(0);
    }
    // C/D: col=ln16 (as/ad idx), row=kq16*4+r (local node) -> sE[col][node]
    *(float4v*)(sE + ln16 * LDE + hu * 16 + kq16 * 4) = acce;
  }

  // ---- phase 1: h = x@W (32x32x16), single pass, 2rt x NCT acc chains ----
  uint32 Ppk[NCT][4][4];  // [ct][kstep t][U0,U1,V0,V1] packed bf16x2
  {
    float16v acc[2][NCT];
#pragma unroll
    for (int rt = 0; rt < 2; ++rt)
#pragma unroll
      for (int ct = 0; ct < NCT; ++ct) acc[rt][ct] = (float16v)0.f;
    const bf16* ap = sX + c * LDX + q * 8;
    const bf16* bp = Wswz + ((colbase + c) * 2 + q) * 8;
#pragma unroll 4
    for (int ks = 0; ks < KS16; ++ks) {
      short8 afr[2];
      afr[0] = *(const short8*)(ap + ks * 16);
      afr[1] = *(const short8*)(ap + 32 * LDX + ks * 16);
      short8 bfr[NCT];
#pragma unroll
      for (int ct = 0; ct < NCT; ++ct)
        bfr[ct] = *(const short8*)(bp + (size_t)ks * (M * 16) + ct * 32 * 16);
      __builtin_amdgcn_s_setprio(1);
#pragma unroll
      for (int rt = 0; rt < 2; ++rt)
#pragma unroll
        for (int ct = 0; ct < NCT; ++ct)
          acc[rt][ct] = __builtin_amdgcn_mfma_f32_32x32x16_bf16(
              afr[rt], bfr[ct], acc[rt][ct], 0, 0, 0);
      __builtin_amdgcn_s_setprio(0);
    }
    // pack h to bf16x2 pairs; acc dies here. C/D row=(r&3)+8*(r>>2)+4q.
#pragma unroll
    for (int rt = 0; rt < 2; ++rt)
#pragma unroll
      for (int ct = 0; ct < NCT; ++ct)
#pragma unroll
        for (int tp = 0; tp < 2; ++tp) {
          Ppk[ct][rt * 2 + tp][0] = packbf2(acc[rt][ct][8 * tp + 0], acc[rt][ct][8 * tp + 1]);
          Ppk[ct][rt * 2 + tp][1] = packbf2(acc[rt][ct][8 * tp + 2], acc[rt][ct][8 * tp + 3]);
          Ppk[ct][rt * 2 + tp][2] = packbf2(acc[rt][ct][8 * tp + 4], acc[rt][ct][8 * tp + 5]);
          Ppk[ct][rt * 2 + tp][3] = packbf2(acc[rt][ct][8 * tp + 6], acc[rt][ct][8 * tp + 7]);
        }
  }

  __syncthreads();  // sX readers done; sE complete

  // ---- P rows in 32x32 A-frag regs; row i = rt*32 + c; k node = tt*16+q*8+j ----
  const float* lsrow = sE + hu * LDE;
  const float* ldrow = sE + (8 + hu) * LDE;
  short8 pfr[2][4];
#pragma unroll
  for (int rt = 0; rt < 2; ++rt) {
    const float ldi = ldrow[rt * 32 + c];
    float pe_[4][8];
    float rsum = 0.f;
#pragma unroll
    for (int tt = 0; tt < 4; ++tt) {
      float4 v0 = *(const float4*)(lsrow + tt * 16 + q * 8);
      float4 v1 = *(const float4*)(lsrow + tt * 16 + q * 8 + 4);
      float ls8[8] = {v0.x, v0.y, v0.z, v0.w, v1.x, v1.y, v1.z, v1.w};
#pragma unroll
      for (int jj = 0; jj < 8; ++jj) {
        float tv = ldi + ls8[jj];
        float e = exp2_hw(fmaxf(tv, 0.2f * tv));  // inputs pre-scaled by log2e
        pe_[tt][jj] = e;
        rsum += e;
      }
    }
    rsum += __shfl_xor(rsum, 32, 64);
    const float ri = rcp_hw(rsum);
#pragma unroll
    for (int tt = 0; tt < 4; ++tt) {
      union { uint32 d[4]; short8 s; } w;
#pragma unroll
      for (int jp = 0; jp < 4; ++jp)
        w.d[jp] = packbf2(pe_[tt][2 * jp] * ri, pe_[tt][2 * jp + 1] * ri);
      pfr[rt][tt] = w.s;
    }
  }

  // ---- per-ct: h C/D -> B-frag (one permlane32_swap per dword pair),
  //      O = P@h, bias, store ----
  // Dest kstep t, lane (c,q'), dword jd: node R = t*16+q'*8+2jd(+1), col c.
  // => q'=0 frag: [U0,U1, partner's U0,U1]; q'=1: [partner's V0,V1, V0,V1].
#pragma unroll
  for (int ct = 0; ct < NCT; ++ct) {
    short8 hfr[4];
#pragma unroll
    for (int tt = 0; tt < 4; ++tt) {
      uint32 U0 = Ppk[ct][tt][0], U1 = Ppk[ct][tt][1];
      uint32 V0 = Ppk[ct][tt][2], V1 = Ppk[ct][tt][3];
      uint32 d0, d1, d2, d3;
      lane32_swap(U0, V0, q, d0, d2);  // d0: own-U/partner-V; d2: partner-U/own-V
      lane32_swap(U1, V1, q, d1, d3);
      union { uint32 d[4]; short8 s; } u;
      u.d[0] = d0; u.d[1] = d1; u.d[2] = d2; u.d[3] = d3;
      hfr[tt] = u.s;
    }
    float16v oacc[2];
    oacc[0] = (float16v)0.f;
    oacc[1] = (float16v)0.f;
    __builtin_amdgcn_s_setprio(1);
#pragma unroll
    for (int tt = 0; tt < 4; ++tt) {
      oacc[0] = __builtin_amdgcn_mfma_f32_32x32x16_bf16(pfr[0][tt], hfr[tt], oacc[0], 0, 0, 0);
      oacc[1] = __builtin_amdgcn_mfma_f32_32x32x16_bf16(pfr[1][tt], hfr[tt], oacc[1], 0, 0, 0);
    }
    __builtin_amdgcn_s_setprio(0);
    const float bv = bias[colbase + ct * 32 + c];
#pragma unroll
    for (int rt = 0; rt < 2; ++rt)
#pragma unroll
      for (int r = 0; r < 16; ++r) {
        float val = oacc[rt][r] + bv;
        int row = rt * 32 + (r & 3) + 8 * (r >> 2) + 4 * q;
        if constexpr (LAST)
          ((float*)sX)[row * 260 + colbase + ct * 32 + c] = val;
        else
          sX[row * LDX + colbase + ct * 32 + c] = f2b1(val);
      }
  }
  __syncthreads();  // x' complete before next layer / mean
}

__global__ __launch_bounds__(THREADS, 4) void gat3_mfma(
    const float* __restrict__ xs, const float* __restrict__ pe,
    const bf16* __restrict__ W1s, const bf16* __restrict__ WE1,
    const float* __restrict__ b1, const bf16* __restrict__ W2s,
    const bf16* __restrict__ WE2, const float* __restrict__ b2,
    const bf16* __restrict__ W3s, const bf16* __restrict__ WE3,
    const float* __restrict__ b3, float* __restrict__ out) {
  extern __shared__ char smem[];
  bf16* sX = (bf16*)smem;              // 64*520*2 = 66560 B
  float* sE = (float*)(smem + 66560);  // 16*68*4 = 4352 B -> total 70912

  const int t = threadIdx.x;
  const int blk = blockIdx.x;  // bs*R = 2048 graphs
  const int bidx = blk >> 8;   // batch index (R=256)

  // x0 = concat(xs, broadcast pos_enc) -> [64][32] bf16, stride LDX
  for (int idx = t; idx < 64 * 32; idx += THREADS) {
    int n = idx >> 5, f = idx & 31;
    float v = (f == 0) ? xs[blk * 64 + n] : pe[(bidx * 64 + n) * 31 + (f - 1)];
    sX[n * LDX + f] = f2b(v);
  }
  __syncthreads();

  gat_layer<32, 512, 64, false>(t, W1s, WE1, b1, sX, sE);
  gat_layer<512, 512, 64, false>(t, W2s, WE2, b2, sX, sE);
  gat_layer<512, 256, 32, true>(t, W3s, WE3, b3, sX, sE);

  // mean over 64 nodes -> [256]
  const float* xf = (const float*)sX;
  if (t < 256) {
    float s = 0.f;
#pragma unroll 8
    for (int i = 0; i < 64; ++i) s += xf[i * 260 + t];
    out[blk * 256 + t] = s * 0.015625f;
  }
}

extern "C" void kernel_launch(void* const* d_in, const int* in_sizes, int n_in,
                              void* d_out, int out_size, void* d_ws, size_t ws_size,
                              hipStream_t stream) {
  const float* xs = (const float*)d_in[0];
  const float* pe = (const float*)d_in[1];
  const float* W1 = (const float*)d_in[2];
  const float* as1 = (const float*)d_in[3];
  const float* ad1 = (const float*)d_in[4];
  const float* b1 = (const float*)d_in[5];
  const float* W2 = (const float*)d_in[6];
  const float* as2 = (const float*)d_in[7];
  const float* ad2 = (const float*)d_in[8];
  const float* b2 = (const float*)d_in[9];
  const float* W3 = (const float*)d_in[10];
  const float* as3 = (const float*)d_in[11];
  const float* ad3 = (const float*)d_in[12];
  const float* b3 = (const float*)d_in[13];

  bf16* Wall = (bf16*)d_ws;          // 409600 elems
  bf16* WEall = Wall + 409600;       // 16896 elems (total 852992 B)
  bf16* W1s = Wall;
  bf16* W2s = Wall + 16384;
  bf16* W3s = Wall + 278528;
  bf16* WE1 = WEall;
  bf16* WE2 = WEall + 512;
  bf16* WE3 = WEall + 8704;

  // parts A (1600 blocks) + B (264 blocks) fused; no inter-dependency
  prep_all<<<dim3(1864), dim3(256), 0, stream>>>(
      W1, W2, W3, as1, ad1, as2, ad2, as3, ad3, Wall, WEall);

  const size_t smem = 70912;
  (void)hipFuncSetAttribute((const void*)gat3_mfma,
                            hipFuncAttributeMaxDynamicSharedMemorySize,
                            (int)smem);
  gat3_mfma<<<dim3(2048), dim3(THREADS), smem, stream>>>(
      xs, pe, W1s, WE1, b1, W2s, WE2, b2, W3s, WE3, b3, (float*)d_out);
}

// Round 6
// 232.262 us; speedup vs baseline: 1.0535x; 1.0535x over previous
//
#include <hip/hip_runtime.h>
#include <hip/hip_bf16.h>

typedef __hip_bfloat16 bf16;
typedef unsigned int uint32;
typedef __attribute__((ext_vector_type(8))) short short8;
typedef __attribute__((ext_vector_type(4))) float float4v;
typedef __attribute__((ext_vector_type(16))) float float16v;

#define THREADS 512
#define LDX 520  // sX row stride in bf16 (16B-aligned rows for ds_read_b128)
#define LDE 68   // sE row stride in f32
#define LOG2E 1.44269504088896340736f

__device__ __forceinline__ bf16 f2b(float x) { return __float2bfloat16(x); }
__device__ __forceinline__ uint32 packbf2(float x, float y) {
  union { __hip_bfloat162 b; uint32 u; } cv;
  cv.b = __float22bfloat162_rn(make_float2(x, y));
  return cv.u;
}
// single f32->bf16 via the packed HW convert (1 op), RNE
__device__ __forceinline__ bf16 f2b1(float x) {
  union { uint32 u; unsigned short s[2]; } cv;
  cv.u = packbf2(x, x);
  union { unsigned short s; bf16 b; } r;
  r.s = cv.s[0];
  return r.b;
}
// 2^x via v_exp_f32 (logits are pre-scaled by log2e at convE time)
__device__ __forceinline__ float exp2_hw(float x) {
#if __has_builtin(__builtin_amdgcn_exp2f)
  return __builtin_amdgcn_exp2f(x);
#else
  float r;
  asm("v_exp_f32 %0, %1" : "=v"(r) : "v"(x));
  return r;
#endif
}
__device__ __forceinline__ float rcp_hw(float x) {
#if __has_builtin(__builtin_amdgcn_rcpf)
  return __builtin_amdgcn_rcpf(x);
#else
  float r;
  asm("v_rcp_f32 %0, %1" : "=v"(r) : "v"(x));
  return r;
#endif
}
// lane<32 <-> lane>=32 half exchange. lo: own(a) for q=0 / partner(b) for q=1.
// hi: partner(a) for q=0 / own(b) for q=1. One v_permlane32_swap yields both;
// old operands die into the swap (saves the 4 select temps of the shfl form).
__device__ __forceinline__ void lane32_swap(uint32 a, uint32 b, int q,
                                            uint32& lo, uint32& hi) {
#if __has_builtin(__builtin_amdgcn_permlane32_swap)
  auto r = __builtin_amdgcn_permlane32_swap(a, b, false, false);
  lo = r[0];
  hi = r[1];
  (void)q;
#else
  uint32 pa = (uint32)__shfl_xor((int)a, 32, 64);
  uint32 pb = (uint32)__shfl_xor((int)b, 32, 64);
  lo = q ? pb : a;
  hi = q ? b : pa;
#endif
}

// ---- fused prep: part A (blocks 0..1599) converts W1/W2/W3 to the 32x32x16
// B-frag layout with COALESCED source reads. Part B (blocks 1600..1863)
// computes the E tiles (W@a_src | W@a_dst per head, scaled by log2e) one WAVE
// per W-row: coalesced float4 row loads + per-lane dot + 8-lane shfl reduce.
__global__ void prep_all(const float* __restrict__ W1, const float* __restrict__ W2,
                         const float* __restrict__ W3,
                         const float* __restrict__ as1, const float* __restrict__ ad1,
                         const float* __restrict__ as2, const float* __restrict__ ad2,
                         const float* __restrict__ as3, const float* __restrict__ ad3,
                         bf16* __restrict__ dst, bf16* __restrict__ dstE) {
  const int b = blockIdx.x;
  const int t = threadIdx.x;
  if (b < 1600) {
    int o = b * 256 + t;  // source-linear over concat(W1,W2,W3): coalesced read
    const float* W;
    int Mlog, loc, dbase;
    if (o < 16384) { W = W1; Mlog = 9; loc = o; dbase = 0; }
    else if (o < 278528) { W = W2; Mlog = 9; loc = o - 16384; dbase = 16384; }
    else { W = W3; Mlog = 8; loc = o - 278528; dbase = 278528; }
    float v = W[loc];
    int M = 1 << Mlog;
    int n = loc & (M - 1), k = loc >> Mlog;
    int kb = k >> 4, q = (k >> 3) & 1, j = k & 7;
    // same dst mapping as before: dst[((kb*M+n)*2+q)*8+j], k = kb*16+q*8+j
    dst[dbase + ((kb * M + n) * 2 + q) * 8 + j] = f2b(v);
    return;
  }
  // ---- part B: one wave per k-row; 1056 rows total (32|512|512) ----
  const int kr = (b - 1600) * 4 + (t >> 6);
  const int l = t & 63;
  const float *W, *as_, *ad_;
  int M, lk, dbase;
  if (kr < 32)       { W = W1; as_ = as1; ad_ = ad1; M = 512; lk = kr;       dbase = 0; }
  else if (kr < 544) { W = W2; as_ = as2; ad_ = ad2; M = 512; lk = kr - 32;  dbase = 512; }
  else               { W = W3; as_ = as3; ad_ = ad3; M = 256; lk = kr - 544; dbase = 8704; }
  const float* wr = W + (size_t)lk * M;
  float ps = 0.f, pd = 0.f;
  if (M == 512) {
    float4 w0 = *(const float4*)(wr + 8 * l);
    float4 w1 = *(const float4*)(wr + 8 * l + 4);
    float4 s0 = *(const float4*)(as_ + 8 * l);
    float4 s1 = *(const float4*)(as_ + 8 * l + 4);
    float4 d0 = *(const float4*)(ad_ + 8 * l);
    float4 d1 = *(const float4*)(ad_ + 8 * l + 4);
    ps = w0.x * s0.x + w0.y * s0.y + w0.z * s0.z + w0.w * s0.w +
         w1.x * s1.x + w1.y * s1.y + w1.z * s1.z + w1.w * s1.w;
    pd = w0.x * d0.x + w0.y * d0.y + w0.z * d0.z + w0.w * d0.w +
         w1.x * d1.x + w1.y * d1.y + w1.z * d1.z + w1.w * d1.w;
  } else {
    float4 w0 = *(const float4*)(wr + 4 * l);
    float4 s0 = *(const float4*)(as_ + 4 * l);
    float4 d0 = *(const float4*)(ad_ + 4 * l);
    ps = w0.x * s0.x + w0.y * s0.y + w0.z * s0.z + w0.w * s0.w;
    pd = w0.x * d0.x + w0.y * d0.y + w0.z * d0.z + w0.w * d0.w;
  }
#pragma unroll
  for (int m = 1; m < 8; m <<= 1) {
    ps += __shfl_xor(ps, m, 64);
    pd += __shfl_xor(pd, m, 64);
  }
  const int j = lk & 7, kc = (lk >> 3) & 3, ks = lk >> 5;
  const int h = l >> 3;
  const int base = dbase + ks * 512 + kc * 8 + j;
  if ((l & 7) == 0) dstE[base + h * 32] = f2b(ps * LOG2E);
  if ((l & 7) == 1) dstE[base + (8 + h) * 32] = f2b(pd * LOG2E);
}

// One GAT layer on 32x32x16 MFMA. Wave w == head w (owns C output cols).
// BARRIER STRUCTURE (R6): E -> bar1 (publish sE) -> [phase1 + pack + softmax,
// UNFENCED so the compiler can hide softmax VALU under the phase1 MFMA/ds
// stream] -> bar2 (all sX reads done) -> [transpose + PV + store] -> bar3.
// pack precedes softmax in source so acc (64 AGPR) dies into Ppk (32) before
// the softmax working set peaks.
// REGISTER DISCIPLINE (R2/R3 lesson): __launch_bounds__(512,4) caps the
// unified VGPR+AGPR file at 128/wave; phase 1 holds 64 AGPR of accumulators.
// pe_ array + IMMEDIATE softmax normalization, oacc scoped per-ct, no extra
// LDS strip: 60+64=124, zero spill. Deferred normalization spilled ~120
// B/thread (WRITE_SIZE 2 MB -> 122-128 MB). Watch WRITE_SIZE as tripwire.
// NO setprio: R5 A/B showed it costs ~5% in this lockstep structure (m190).
template <int K, int M, int C, bool LAST>
__device__ __forceinline__ void gat_layer(
    int t, const bf16* __restrict__ Wswz, const bf16* __restrict__ WE,
    const float* __restrict__ bias, bf16* sX, float* sE) {
  constexpr int NCT = C / 32;   // 32-col tiles per wave (2 or 1)
  constexpr int KS16 = K / 16;  // 32x32x16 k-steps
  constexpr int KSE = K / 32;   // 16x16x32 k-steps for E
  const int lane = t & 63;
  const int hu = __builtin_amdgcn_readfirstlane(t >> 6);  // wave/head id
  const int c = lane & 31, q = lane >> 5;
  const int ln16 = lane & 15, kq16 = lane >> 4;
  const int colbase = hu * C;

  // ---- E-tile (ls|ld for ALL heads), waves 0-3, 16x16x32 path ----
  if (hu < 4) {
    float4v acce = (float4v)0.f;
#pragma unroll
    for (int ks = 0; ks < KSE; ++ks) {
      short8 afrE = *(const short8*)(sX + (hu * 16 + ln16) * LDX + ks * 32 + kq16 * 8);
      short8 efr = *(const short8*)(WE + ks * 512 + ln16 * 32 + kq16 * 8);
      acce = __builtin_amdgcn_mfma_f32_16x16x32_bf16(afrE, efr, acce, 0, 0, 0);
    }
    // C/D: col=ln16 (as/ad idx), row=kq16*4+r (local node) -> sE[col][node]
    *(float4v*)(sE + ln16 * LDE + hu * 16 + kq16 * 4) = acce;
  }
  __syncthreads();  // bar1: sE visible to all waves; sX untouched so far

  // ---- phase 1: h = x@W (32x32x16), single pass, 2rt x NCT acc chains ----
  uint32 Ppk[NCT][4][4];  // [ct][kstep t][U0,U1,V0,V1] packed bf16x2
  {
    float16v acc[2][NCT];
#pragma unroll
    for (int rt = 0; rt < 2; ++rt)
#pragma unroll
      for (int ct = 0; ct < NCT; ++ct) acc[rt][ct] = (float16v)0.f;
    const bf16* ap = sX + c * LDX + q * 8;
    const bf16* bp = Wswz + ((colbase + c) * 2 + q) * 8;
#pragma unroll 4
    for (int ks = 0; ks < KS16; ++ks) {
      short8 afr[2];
      afr[0] = *(const short8*)(ap + ks * 16);
      afr[1] = *(const short8*)(ap + 32 * LDX + ks * 16);
      short8 bfr[NCT];
#pragma unroll
      for (int ct = 0; ct < NCT; ++ct)
        bfr[ct] = *(const short8*)(bp + (size_t)ks * (M * 16) + ct * 32 * 16);
#pragma unroll
      for (int rt = 0; rt < 2; ++rt)
#pragma unroll
        for (int ct = 0; ct < NCT; ++ct)
          acc[rt][ct] = __builtin_amdgcn_mfma_f32_32x32x16_bf16(
              afr[rt], bfr[ct], acc[rt][ct], 0, 0, 0);
    }
    // pack h to bf16x2 pairs; acc dies here. C/D row=(r&3)+8*(r>>2)+4q.
#pragma unroll
    for (int rt = 0; rt < 2; ++rt)
#pragma unroll
      for (int ct = 0; ct < NCT; ++ct)
#pragma unroll
        for (int tp = 0; tp < 2; ++tp) {
          Ppk[ct][rt * 2 + tp][0] = packbf2(acc[rt][ct][8 * tp + 0], acc[rt][ct][8 * tp + 1]);
          Ppk[ct][rt * 2 + tp][1] = packbf2(acc[rt][ct][8 * tp + 2], acc[rt][ct][8 * tp + 3]);
          Ppk[ct][rt * 2 + tp][2] = packbf2(acc[rt][ct][8 * tp + 4], acc[rt][ct][8 * tp + 5]);
          Ppk[ct][rt * 2 + tp][3] = packbf2(acc[rt][ct][8 * tp + 6], acc[rt][ct][8 * tp + 7]);
        }
  }

  // ---- softmax: P rows in 32x32 A-frag regs; row i = rt*32 + c;
  //      k node = tt*16+q*8+j. Reads only sE (ready since bar1) — in the
  //      same unfenced region as phase1, so VALU can hide under MFMA. ----
  const float* lsrow = sE + hu * LDE;
  const float* ldrow = sE + (8 + hu) * LDE;
  short8 pfr[2][4];
#pragma unroll
  for (int rt = 0; rt < 2; ++rt) {
    const float ldi = ldrow[rt * 32 + c];
    float pe_[4][8];
    float rsum = 0.f;
#pragma unroll
    for (int tt = 0; tt < 4; ++tt) {
      float4 v0 = *(const float4*)(lsrow + tt * 16 + q * 8);
      float4 v1 = *(const float4*)(lsrow + tt * 16 + q * 8 + 4);
      float ls8[8] = {v0.x, v0.y, v0.z, v0.w, v1.x, v1.y, v1.z, v1.w};
#pragma unroll
      for (int jj = 0; jj < 8; ++jj) {
        float tv = ldi + ls8[jj];
        float e = exp2_hw(fmaxf(tv, 0.2f * tv));  // inputs pre-scaled by log2e
        pe_[tt][jj] = e;
        rsum += e;
      }
    }
    rsum += __shfl_xor(rsum, 32, 64);
    const float ri = rcp_hw(rsum);
#pragma unroll
    for (int tt = 0; tt < 4; ++tt) {
      union { uint32 d[4]; short8 s; } w;
#pragma unroll
      for (int jp = 0; jp < 4; ++jp)
        w.d[jp] = packbf2(pe_[tt][2 * jp] * ri, pe_[tt][2 * jp + 1] * ri);
      pfr[rt][tt] = w.s;
    }
  }

  __syncthreads();  // bar2: every wave's sX reads (E + phase1) are complete

  // ---- per-ct: h C/D -> B-frag (one permlane32_swap per dword pair),
  //      O = P@h, bias, store to sX ----
  // Dest kstep t, lane (c,q'), dword jd: node R = t*16+q'*8+2jd(+1), col c.
  // => q'=0 frag: [U0,U1, partner's U0,U1]; q'=1: [partner's V0,V1, V0,V1].
#pragma unroll
  for (int ct = 0; ct < NCT; ++ct) {
    short8 hfr[4];
#pragma unroll
    for (int tt = 0; tt < 4; ++tt) {
      uint32 U0 = Ppk[ct][tt][0], U1 = Ppk[ct][tt][1];
      uint32 V0 = Ppk[ct][tt][2], V1 = Ppk[ct][tt][3];
      uint32 d0, d1, d2, d3;
      lane32_swap(U0, V0, q, d0, d2);  // d0: own-U/partner-V; d2: partner-U/own-V
      lane32_swap(U1, V1, q, d1, d3);
      union { uint32 d[4]; short8 s; } u;
      u.d[0] = d0; u.d[1] = d1; u.d[2] = d2; u.d[3] = d3;
      hfr[tt] = u.s;
    }
    float16v oacc[2];
    oacc[0] = (float16v)0.f;
    oacc[1] = (float16v)0.f;
#pragma unroll
    for (int tt = 0; tt < 4; ++tt) {
      oacc[0] = __builtin_amdgcn_mfma_f32_32x32x16_bf16(pfr[0][tt], hfr[tt], oacc[0], 0, 0, 0);
      oacc[1] = __builtin_amdgcn_mfma_f32_32x32x16_bf16(pfr[1][tt], hfr[tt], oacc[1], 0, 0, 0);
    }
    const float bv = bias[colbase + ct * 32 + c];
#pragma unroll
    for (int rt = 0; rt < 2; ++rt)
#pragma unroll
      for (int r = 0; r < 16; ++r) {
        float val = oacc[rt][r] + bv;
        int row = rt * 32 + (r & 3) + 8 * (r >> 2) + 4 * q;
        if constexpr (LAST)
          ((float*)sX)[row * 260 + colbase + ct * 32 + c] = val;
        else
          sX[row * LDX + colbase + ct * 32 + c] = f2b1(val);
      }
  }
  __syncthreads();  // bar3: x' complete before next layer / mean
}

__global__ __launch_bounds__(THREADS, 4) void gat3_mfma(
    const float* __restrict__ xs, const float* __restrict__ pe,
    const bf16* __restrict__ W1s, const bf16* __restrict__ WE1,
    const float* __restrict__ b1, const bf16* __restrict__ W2s,
    const bf16* __restrict__ WE2, const float* __restrict__ b2,
    const bf16* __restrict__ W3s, const bf16* __restrict__ WE3,
    const float* __restrict__ b3, float* __restrict__ out) {
  extern __shared__ char smem[];
  bf16* sX = (bf16*)smem;              // 64*520*2 = 66560 B
  float* sE = (float*)(smem + 66560);  // 16*68*4 = 4352 B -> total 70912

  const int t = threadIdx.x;
  const int blk = blockIdx.x;  // bs*R = 2048 graphs
  const int bidx = blk >> 8;   // batch index (R=256)

  // x0 = concat(xs, broadcast pos_enc) -> [64][32] bf16, stride LDX
  for (int idx = t; idx < 64 * 32; idx += THREADS) {
    int n = idx >> 5, f = idx & 31;
    float v = (f == 0) ? xs[blk * 64 + n] : pe[(bidx * 64 + n) * 31 + (f - 1)];
    sX[n * LDX + f] = f2b(v);
  }
  __syncthreads();

  gat_layer<32, 512, 64, false>(t, W1s, WE1, b1, sX, sE);
  gat_layer<512, 512, 64, false>(t, W2s, WE2, b2, sX, sE);
  gat_layer<512, 256, 32, true>(t, W3s, WE3, b3, sX, sE);

  // mean over 64 nodes -> [256]
  const float* xf = (const float*)sX;
  if (t < 256) {
    float s = 0.f;
#pragma unroll 8
    for (int i = 0; i < 64; ++i) s += xf[i * 260 + t];
    out[blk * 256 + t] = s * 0.015625f;
  }
}

extern "C" void kernel_launch(void* const* d_in, const int* in_sizes, int n_in,
                              void* d_out, int out_size, void* d_ws, size_t ws_size,
                              hipStream_t stream) {
  const float* xs = (const float*)d_in[0];
  const float* pe = (const float*)d_in[1];
  const float* W1 = (const float*)d_in[2];
  const float* as1 = (const float*)d_in[3];
  const float* ad1 = (const float*)d_in[4];
  const float* b1 = (const float*)d_in[5];
  const float* W2 = (const float*)d_in[6];
  const float* as2 = (const float*)d_in[7];
  const float* ad2 = (const float*)d_in[8];
  const float* b2 = (const float*)d_in[9];
  const float* W3 = (const float*)d_in[10];
  const float* as3 = (const float*)d_in[11];
  const float* ad3 = (const float*)d_in[12];
  const float* b3 = (const float*)d_in[13];

  bf16* Wall = (bf16*)d_ws;          // 409600 elems
  bf16* WEall = Wall + 409600;       // 16896 elems (total 852992 B)
  bf16* W1s = Wall;
  bf16* W2s = Wall + 16384;
  bf16* W3s = Wall + 278528;
  bf16* WE1 = WEall;
  bf16* WE2 = WEall + 512;
  bf16* WE3 = WEall + 8704;

  // parts A (1600 blocks) + B (264 blocks) fused; no inter-dependency
  prep_all<<<dim3(1864), dim3(256), 0, stream>>>(
      W1, W2, W3, as1, ad1, as2, ad2, as3, ad3, Wall, WEall);

  // one-time: raise dynamic-smem cap (host-side; keep out of steady-state)
  static bool smem_inited = false;
  if (!smem_inited) {
    (void)hipFuncSetAttribute((const void*)gat3_mfma,
                              hipFuncAttributeMaxDynamicSharedMemorySize,
                              70912);
    smem_inited = true;
  }
  gat3_mfma<<<dim3(2048), dim3(THREADS), 70912, stream>>>(
      xs, pe, W1s, WE1, b1, W2s, WE2, b2, W3s, WE3, b3, (float*)d_out);
}